// Round 21
// baseline (3689.564 us; speedup 1.0000x reference)
//
#include <hip/hip_runtime.h>
#include <cstdint>
#include <cstddef>

// Bidirectional LSTM  B=32 T=1024 D=512 H=256 (torch gate order i,f,g,o), fp32 in/out.
//
// Phase 1: xp = x @ Wih^T + bias  (fp16 MFMA GEMM, xp fp16)
// Phase 2: ZERO-COMMUNICATION i8 MFMA recurrence, NO gate bounce:
//   D-tile layout (16x16: col=lane&15, row=(lane>>4)*4+reg) + column-redundant B
//   means every lane holds rows lq*4..lq*4+3 of ALL 8 tiles in registers. Remap
//   lane->output n = ((lane>>2)&1)*16 + lq*4 + (lane&3) (cols 8-15 redundant):
//   all 4 gates of output n are IN-REGISTER -> extract via cndmask ternaries on
//   values (no runtime array indexing -> no scratch), activate, write h. The LDS
//   gate-bounce round trip (~300cy serial/step) is deleted. LDS = 512B h buffer.
//   One block per (dir,batch) chain; all 32 i8 A-frags (mfma_i32_16x16x64_i8) in
//   registers; h re-quantized to i8 each step; xp prefetched one step ahead;
//   rcp-based activation; 1 lgkm barrier/step. Numerics identical to R18/R19.

typedef unsigned int   uint;
typedef unsigned short ushort;

constexpr int Tn = 1024;
constexpr int Bn = 32;
constexpr int Dn = 512;
constexpr int Hn = 256;
constexpr int NC = 2048;          // 2 dirs * 4H
constexpr int KT = 512;           // K of the input projection

typedef _Float16 half8  __attribute__((ext_vector_type(8)));
typedef float    f32x4  __attribute__((ext_vector_type(4)));
typedef int      i32x4  __attribute__((ext_vector_type(4)));

__device__ __forceinline__ ushort f2h(float f) {
  _Float16 h = (_Float16)f;               // RNE
  return __builtin_bit_cast(ushort, h);
}
__device__ __forceinline__ float h2f(ushort s) {
  return (float)__builtin_bit_cast(_Float16, s);
}
__device__ __forceinline__ uint packh(float a, float b) {
  return (uint)f2h(a) | ((uint)f2h(b) << 16);
}
__device__ __forceinline__ f32x4 mf(uint4 a, uint4 b, f32x4 c) {
  return __builtin_amdgcn_mfma_f32_16x16x32_f16(
      __builtin_bit_cast(half8, a), __builtin_bit_cast(half8, b), c, 0, 0, 0);
}
__device__ __forceinline__ i32x4 mfi8(uint4 a, uint4 b, i32x4 c) {
  return __builtin_amdgcn_mfma_i32_16x16x64_i8(
      __builtin_bit_cast(i32x4, a), __builtin_bit_cast(i32x4, b), c, 0, 0, 0);
}

#if defined(__has_builtin)
#  if __has_builtin(__builtin_amdgcn_rcpf)
#    define RCPF(x) __builtin_amdgcn_rcpf(x)
#  endif
#endif
#ifndef RCPF
#  define RCPF(x) (1.f / (x))
#endif

__device__ __forceinline__ float sigr_(float x) {      // rcp handles saturation
  return RCPF(1.f + __expf(-x));
}
__device__ __forceinline__ float tanhr_(float x) {
  float e = __expf(2.f * x);
  return fmaf(-2.f, RCPF(e + 1.f), 1.f);
}

// lgkm-only block barrier (no vmcnt drain: out-stores stay in flight)
__device__ __forceinline__ void barrier_lgkm() {
  asm volatile("s_waitcnt lgkmcnt(0)" ::: "memory");
  __builtin_amdgcn_s_barrier();
}

// ---------------- prep kernels ----------------

__global__ void k_prep_a(const float* __restrict__ x, ushort* __restrict__ a16, long nquad) {
  long i4 = (long)blockIdx.x * blockDim.x + threadIdx.x;
  if (i4 >= nquad) return;
  const float4 v = ((const float4*)x)[i4];
  ushort4 o;
  o.x = f2h(v.x); o.y = f2h(v.y); o.z = f2h(v.z); o.w = f2h(v.w);
  ((ushort4*)a16)[i4] = o;
}

__global__ void k_prep_w(const float* __restrict__ wf, const float* __restrict__ wb,
                         const float* __restrict__ bf1, const float* __restrict__ bf2,
                         const float* __restrict__ bb1, const float* __restrict__ bb2,
                         ushort* __restrict__ w16, float* __restrict__ biasc) {
  long i4 = (long)blockIdx.x * blockDim.x + threadIdx.x;
  if (i4 >= (long)NC * (KT / 4)) return;
  int n = (int)(i4 >> 7);
  int k4 = (int)(i4 & 127);
  int dir = n >> 10, g = n & 1023;
  const float* w = dir ? wb : wf;
  const float4 v = ((const float4*)(w + (size_t)g * Dn))[k4];
  ushort4 o;
  o.x = f2h(v.x); o.y = f2h(v.y); o.z = f2h(v.z); o.w = f2h(v.w);
  ((ushort4*)w16)[i4] = o;
  if (k4 == 0) biasc[n] = dir ? (bb1[g] + bb2[g]) : (bf1[g] + bf2[g]);
}

// per-row quant scale: sq[dir*1024+row] = rowmax/127
__global__ void k_scale(const float* __restrict__ whhF, const float* __restrict__ whhB,
                        float* __restrict__ sq) {
  int t = blockIdx.x * blockDim.x + threadIdx.x;
  if (t >= 2048) return;
  int dir = t >> 10, row = t & 1023;
  const float* w = (dir ? whhB : whhF) + (size_t)row * Hn;
  float m = 0.f;
  for (int i = 0; i < Hn; ++i) m = fmaxf(m, fabsf(w[i]));
  sq[t] = fmaxf(m, 1e-30f) / 127.f;
}

// Whh -> i8 A-frags. WF8[dir][w][frag=kt*8+m][lane] (uint4 = 16 x i8).
// m: g=m>>1, j=m&1; row = (g*16+2w+j)*16 + (lane&15); k = kt*64 + (lane>>4)*16 + 0..15.
__global__ void k_prep_whh8(const float* __restrict__ whhF, const float* __restrict__ whhB,
                            const float* __restrict__ sq, uint4* __restrict__ WF8) {
  int t = blockIdx.x * blockDim.x + threadIdx.x;   // 0 .. 32767
  if (t >= 2 * 8 * 32 * 64) return;
  int lane = t & 63;
  int frag = (t >> 6) & 31;
  int w    = (t >> 11) & 7;
  int dir  = (t >> 14) & 1;
  int m  = frag & 7, kt = frag >> 3;
  int g = m >> 1, j = m & 1;
  int row = (g * 16 + 2 * w + j) * 16 + (lane & 15);
  int kb  = kt * 64 + (lane >> 4) * 16;
  const float* whh = dir ? whhB : whhF;
  const float* src = whh + (size_t)row * Hn + kb;
  float inv = 1.f / sq[dir * 1024 + row];          // = 127/rowmax
  uint pk[4];
#pragma unroll
  for (int q = 0; q < 4; ++q) {
    uint v = 0;
#pragma unroll
    for (int b = 0; b < 4; ++b) {
      float f = src[q * 4 + b] * inv;
      int iq = (int)rintf(fminf(fmaxf(f, -127.f), 127.f));
      v |= ((uint)(unsigned char)(signed char)iq) << (8 * b);
    }
    pk[q] = v;
  }
  WF8[t] = (uint4){pk[0], pk[1], pk[2], pk[3]};
}

__global__ void k_bad(float* __restrict__ out, int n) {
  int i = blockIdx.x * blockDim.x + threadIdx.x;
  if (i < n) out[i] = 54321.f;
}

// ---------------- phase 1: fp16 MFMA GEMM (unchanged) ----------------

__device__ __forceinline__ void gload_lds16(const void* g, void* l) {
  __builtin_amdgcn_global_load_lds((const __attribute__((address_space(1))) void*)g,
                                   (__attribute__((address_space(3))) void*)l, 16, 0, 0);
}

__global__ __launch_bounds__(256) void k_gemm(const ushort* __restrict__ A,
                                              const ushort* __restrict__ W,
                                              const float* __restrict__ biasc,
                                              ushort* __restrict__ xp) {
  __shared__ __align__(16) ushort As[128 * 32];
  __shared__ __align__(16) ushort Bs[128 * 32];
  const int bid = blockIdx.x;
  const int m0 = (bid >> 4) * 128;
  const int n0 = (bid & 15) * 128;
  const int tid = threadIdx.x;
  const int wid = tid >> 6, lane = tid & 63;
  const int wr = wid >> 1, wcq = wid & 1;
  const int l16 = lane & 15, lq = lane >> 4;

  f32x4 acc[4][4] = {};

  for (int kt = 0; kt < KT; kt += 32) {
    __syncthreads();
#pragma unroll
    for (int i = 0; i < 2; ++i) {
      int ch = wid * 2 + i;
      int p = ch * 64 + lane;
      int r = p >> 2, gp = p & 3;
      int gs = gp ^ ((r >> 1) & 3);
      gload_lds16(A + (size_t)(m0 + r) * KT + kt + gs * 8, (char*)As + ch * 1024);
      gload_lds16(W + (size_t)(n0 + r) * KT + kt + gs * 8, (char*)Bs + ch * 1024);
    }
    __syncthreads();

    half8 af[4], bfr[4];
#pragma unroll
    for (int mfi = 0; mfi < 4; ++mfi) {
      int row = wr * 64 + mfi * 16 + l16;
      int g = lq ^ ((row >> 1) & 3);
      af[mfi] = *(const half8*)((const char*)As + row * 64 + g * 16);
    }
#pragma unroll
    for (int nf = 0; nf < 4; ++nf) {
      int row = wcq * 64 + nf * 16 + l16;
      int g = lq ^ ((row >> 1) & 3);
      bfr[nf] = *(const half8*)((const char*)Bs + row * 64 + g * 16);
    }
#pragma unroll
    for (int mfi = 0; mfi < 4; ++mfi)
#pragma unroll
      for (int nf = 0; nf < 4; ++nf)
        acc[mfi][nf] = __builtin_amdgcn_mfma_f32_16x16x32_f16(af[mfi], bfr[nf], acc[mfi][nf], 0, 0, 0);
  }

#pragma unroll
  for (int nf = 0; nf < 4; ++nf) {
    int col = n0 + wcq * 64 + nf * 16 + l16;
    float bv = biasc[col];
#pragma unroll
    for (int mfi = 0; mfi < 4; ++mfi) {
      int rbase = m0 + wr * 64 + mfi * 16 + lq * 4;
#pragma unroll
      for (int i = 0; i < 4; ++i)
        xp[(size_t)(rbase + i) * NC + col] = f2h(acc[mfi][nf][i] + bv);
    }
  }
}

// ---------------- phase 2: zero-comm i8 recurrence, bounce-free ----------------
// bid: dir = &1, bl = >>1. Wave w owns outputs 32w..32w+31 (tiles g*16+2w+j).
// Lane -> output: n = jsel*16 + lq*4 + isel, jsel=(lane>>2)&1, isel=lane&3;
// cols 8-15 compute redundantly, only (lane&15)<8 writes. Gates extracted from
// acc registers via value-selects (no LDS bounce).

__global__ __launch_bounds__(512, 2) void k_lstm(const uint4* __restrict__ WF8,
                                                 const float* __restrict__ sq,
                                                 const ushort* __restrict__ xp,
                                                 float* __restrict__ out,
                                                 int b_base) {
  const int dir = blockIdx.x & 1;
  const int bl  = blockIdx.x >> 1;
  const int tid = threadIdx.x;
  const int w    = tid >> 6;
  const int lane = tid & 63;
  const int lq   = lane >> 4;
  const int jsel = (lane >> 2) & 1;
  const int isel = lane & 3;
  const int n    = jsel * 16 + lq * 4 + isel;  // this lane's output (0..31)
  const bool wr8 = (lane & 15) < 8;            // unique-writer mask

  __shared__ __align__(16) char hq[2][256];    // i8 h, parity double-buffered

  // ---- persistent weights: all 32 i8 frags in registers ----
  const uint4* wfb = WF8 + (size_t)((dir * 8 + w) * 32) * 64 + lane;
  uint4 wA[32];
#pragma unroll
  for (int f = 0; f < 32; ++f) wA[f] = wfb[(size_t)f * 64];

  // per-output dequant scales (4 gate rows), includes the 1/127 h-scale
  float fdq[4];
#pragma unroll
  for (int g = 0; g < 4; ++g)
    fdq[g] = sq[dir * 1024 + g * 256 + 32 * w + n] * (1.f / 127.f);

  if (tid < 128) ((uint*)hq)[tid] = 0;         // h_{-1} = 0 (both buffers)
  float creg = 0.f;
  __syncthreads();

  const int dstep = dir ? -1 : 1;
  const int t0 = dir ? (Tn - 1) : 0;
  const ptrdiff_t xstr = (ptrdiff_t)dstep * NC;
  const ptrdiff_t ostr = (ptrdiff_t)dstep * 512;
  const ushort* px = xp + (size_t)(bl * Tn + t0) * NC + dir * 1024 + 32 * w + n;
  float* pout = out + (size_t)((b_base + bl) * Tn + t0) * 512 + dir * 256 + 32 * w + n;

  // preload xp for t=0 (fp32)
  float xc0 = h2f(px[0]), xc1 = h2f(px[256]), xc2 = h2f(px[512]), xc3 = h2f(px[768]);

  int cur = 0;
#pragma unroll 1
  for (int t = 0; t < Tn; ++t) {
    // B-frags: 16 i8 h-values per kt (uniform per lane-quad)
    uint4 bq[4];
#pragma unroll
    for (int kt = 0; kt < 4; ++kt)
      bq[kt] = *(const uint4*)(hq[cur] + kt * 64 + lq * 16);

    // prefetch xp for t+1 (consumed at NEXT step's tail)
    float xn0 = 0.f, xn1 = 0.f, xn2 = 0.f, xn3 = 0.f;
    if (t + 1 < Tn) {
      px += xstr;
      xn0 = h2f(px[0]); xn1 = h2f(px[256]); xn2 = h2f(px[512]); xn3 = h2f(px[768]);
    }

    i32x4 acc[8];
#pragma unroll
    for (int m = 0; m < 8; ++m) acc[m] = (i32x4){0, 0, 0, 0};
#pragma unroll
    for (int kt = 0; kt < 4; ++kt)
#pragma unroll
      for (int m = 0; m < 8; ++m)
        acc[m] = mfi8(wA[kt * 8 + m], bq[kt], acc[m]);

    // ---- in-register gate extraction: acc[g*2+jsel][isel] via value-selects ----
    const float xc[4] = {xc0, xc1, xc2, xc3};
    float act[4];
#pragma unroll
    for (int g = 0; g < 4; ++g) {
      i32x4 a = jsel ? acc[g * 2 + 1] : acc[g * 2];
      int v = (isel == 0) ? a.x : (isel == 1) ? a.y : (isel == 2) ? a.z : a.w;
      float gv = (float)v * fdq[g] + xc[g];
      act[g] = (g == 2) ? tanhr_(gv) : sigr_(gv);
    }

    // tail: cell update (registers only)
    creg = act[1] * creg + act[0] * act[2];
    float h = act[3] * tanhr_(creg);
    if (wr8) {
      *pout = h;                                   // fp32 output (drains lazily)
      int q = (int)rintf(h * 127.f);               // |h|<1 -> q in [-127,127]
      hq[cur ^ 1][32 * w + n] = (char)q;           // i8 h for next step
    }
    pout += ostr;
    xc0 = xn0; xc1 = xn1; xc2 = xn2; xc3 = xn3;
    barrier_lgkm();                                // h_t visible to all waves
    cur ^= 1;
  }
}

// ---------------- host ----------------

extern "C" void kernel_launch(void* const* d_in, const int* in_sizes, int n_in,
                              void* d_out, int out_size, void* d_ws, size_t ws_size,
                              hipStream_t stream) {
  const float* x     = (const float*)d_in[0];
  const float* Wih_f = (const float*)d_in[1];
  const float* Whh_f = (const float*)d_in[2];
  const float* bih_f = (const float*)d_in[3];
  const float* bhh_f = (const float*)d_in[4];
  const float* Wih_b = (const float*)d_in[5];
  const float* Whh_b = (const float*)d_in[6];
  const float* bib_b = (const float*)d_in[7];
  const float* bhh_b = (const float*)d_in[8];
  float* out = (float*)d_out;

  const size_t szW16  = (size_t)NC * KT * 2;            // 2 MiB
  const size_t szBias = (size_t)NC * 4;
  const size_t szSq   = 2048 * 4;                       // 8 KiB row scales
  const size_t szWF8  = (size_t)2 * 8 * 32 * 64 * 16;   // 512 KiB i8 frag buffer

  int c = 0;
  size_t szA16 = 0, szXp = 0;
  for (int cc = 1; cc <= 16; cc *= 2) {
    size_t a = (size_t)(Bn / cc) * Tn * KT * 2;
    size_t p = (size_t)(Bn / cc) * Tn * NC * 2;
    if (szW16 + szBias + szSq + szWF8 + a + p <= ws_size) { c = cc; szA16 = a; szXp = p; break; }
  }
  if (c == 0) {
    k_bad<<<(out_size + 255) / 256, 256, 0, stream>>>(out, out_size);
    return;
  }

  char* ws = (char*)d_ws;
  ushort* W16   = (ushort*)ws;
  float*  biasc = (float*)(ws + szW16);
  float*  sq    = (float*)(ws + szW16 + szBias);
  uint4*  WF8   = (uint4*)(ws + szW16 + szBias + szSq);
  ushort* A16   = (ushort*)(ws + szW16 + szBias + szSq + szWF8);
  ushort* xp    = (ushort*)(ws + szW16 + szBias + szSq + szWF8 + szA16);

  {
    long n4 = (long)NC * (KT / 4);
    k_prep_w<<<(int)((n4 + 255) / 256), 256, 0, stream>>>(Wih_f, Wih_b, bih_f, bhh_f,
                                                          bib_b, bhh_b, W16, biasc);
  }
  k_scale<<<8, 256, 0, stream>>>(Whh_f, Whh_b, sq);
  k_prep_whh8<<<(2 * 8 * 32 * 64) / 256, 256, 0, stream>>>(Whh_f, Whh_b, sq, WF8);

  const int sizeB = Bn / c;
  for (int cb = 0; cb < c; ++cb) {
    const int b_base = cb * sizeB;
    {
      long nquad = (long)sizeB * Tn * KT / 4;
      k_prep_a<<<(int)((nquad + 255) / 256), 256, 0, stream>>>(
          x + (size_t)b_base * Tn * Dn, A16, nquad);
    }
    k_gemm<<<dim3(sizeB * 8 * 16), dim3(256), 0, stream>>>(A16, W16, biasc, xp);
    k_lstm<<<dim3(2 * sizeB), dim3(512), 0, stream>>>(WF8, sq, xp, out, b_base);
  }
}

// Round 22
// 1280.861 us; speedup vs baseline: 2.8805x; 2.8805x over previous
//
#include <hip/hip_runtime.h>
#include <cstdint>
#include <cstddef>

// Bidirectional LSTM  B=32 T=1024 D=512 H=256 (torch gate order i,f,g,o), fp32 in/out.
//
// BEST (Round-19 config, reverted after R20/R21 regressions): total ~1278us.
// Phase 1: xp = x @ Wih^T + bias  (fp16 MFMA GEMM, xp fp16)
// Phase 2: ZERO-COMMUNICATION i8 MFMA recurrence:
//   (1) xp prefetched one FULL step ahead (fp32 in regs) -- tail has no global dep;
//   (2) j=0 gate-bounce written right after its 4 chains finish, hiding under the
//       j=1 MFMAs (gbuf decouples matrix pipe from VALU tail -- removing it (R21)
//       serialized the schedule, 3x regression);
//   (3) activation via v_rcp_f32 (rcp(inf)=0 gives exact saturation).
//   One block per (dir,batch) chain; all 32 i8 A-frags (mfma_i32_16x16x64_i8) in
//   registers (per-row symmetric quant, s=rowmax/127); h re-quantized to i8 each
//   step; i32 accum exact; 1 lgkm barrier/step. absmax 0.0117 < 0.0195 threshold.

typedef unsigned int   uint;
typedef unsigned short ushort;

constexpr int Tn = 1024;
constexpr int Bn = 32;
constexpr int Dn = 512;
constexpr int Hn = 256;
constexpr int NC = 2048;          // 2 dirs * 4H
constexpr int KT = 512;           // K of the input projection

typedef _Float16 half8  __attribute__((ext_vector_type(8)));
typedef float    f32x4  __attribute__((ext_vector_type(4)));
typedef int      i32x4  __attribute__((ext_vector_type(4)));

__device__ __forceinline__ ushort f2h(float f) {
  _Float16 h = (_Float16)f;               // RNE
  return __builtin_bit_cast(ushort, h);
}
__device__ __forceinline__ float h2f(ushort s) {
  return (float)__builtin_bit_cast(_Float16, s);
}
__device__ __forceinline__ uint packh(float a, float b) {
  return (uint)f2h(a) | ((uint)f2h(b) << 16);
}
__device__ __forceinline__ f32x4 mf(uint4 a, uint4 b, f32x4 c) {
  return __builtin_amdgcn_mfma_f32_16x16x32_f16(
      __builtin_bit_cast(half8, a), __builtin_bit_cast(half8, b), c, 0, 0, 0);
}
__device__ __forceinline__ i32x4 mfi8(uint4 a, uint4 b, i32x4 c) {
  return __builtin_amdgcn_mfma_i32_16x16x64_i8(
      __builtin_bit_cast(i32x4, a), __builtin_bit_cast(i32x4, b), c, 0, 0, 0);
}

#if defined(__has_builtin)
#  if __has_builtin(__builtin_amdgcn_rcpf)
#    define RCPF(x) __builtin_amdgcn_rcpf(x)
#  endif
#endif
#ifndef RCPF
#  define RCPF(x) (1.f / (x))
#endif

__device__ __forceinline__ float sigr_(float x) {      // rcp handles saturation
  return RCPF(1.f + __expf(-x));
}
__device__ __forceinline__ float tanhr_(float x) {
  float e = __expf(2.f * x);
  return fmaf(-2.f, RCPF(e + 1.f), 1.f);
}

// lgkm-only block barrier (no vmcnt drain: out-stores stay in flight)
__device__ __forceinline__ void barrier_lgkm() {
  asm volatile("s_waitcnt lgkmcnt(0)" ::: "memory");
  __builtin_amdgcn_s_barrier();
}

// ---------------- prep kernels ----------------

__global__ void k_prep_a(const float* __restrict__ x, ushort* __restrict__ a16, long nquad) {
  long i4 = (long)blockIdx.x * blockDim.x + threadIdx.x;
  if (i4 >= nquad) return;
  const float4 v = ((const float4*)x)[i4];
  ushort4 o;
  o.x = f2h(v.x); o.y = f2h(v.y); o.z = f2h(v.z); o.w = f2h(v.w);
  ((ushort4*)a16)[i4] = o;
}

__global__ void k_prep_w(const float* __restrict__ wf, const float* __restrict__ wb,
                         const float* __restrict__ bf1, const float* __restrict__ bf2,
                         const float* __restrict__ bb1, const float* __restrict__ bb2,
                         ushort* __restrict__ w16, float* __restrict__ biasc) {
  long i4 = (long)blockIdx.x * blockDim.x + threadIdx.x;
  if (i4 >= (long)NC * (KT / 4)) return;
  int n = (int)(i4 >> 7);
  int k4 = (int)(i4 & 127);
  int dir = n >> 10, g = n & 1023;
  const float* w = dir ? wb : wf;
  const float4 v = ((const float4*)(w + (size_t)g * Dn))[k4];
  ushort4 o;
  o.x = f2h(v.x); o.y = f2h(v.y); o.z = f2h(v.z); o.w = f2h(v.w);
  ((ushort4*)w16)[i4] = o;
  if (k4 == 0) biasc[n] = dir ? (bb1[g] + bb2[g]) : (bf1[g] + bf2[g]);
}

// per-row quant scale: sq[dir*1024+row] = rowmax/127
__global__ void k_scale(const float* __restrict__ whhF, const float* __restrict__ whhB,
                        float* __restrict__ sq) {
  int t = blockIdx.x * blockDim.x + threadIdx.x;
  if (t >= 2048) return;
  int dir = t >> 10, row = t & 1023;
  const float* w = (dir ? whhB : whhF) + (size_t)row * Hn;
  float m = 0.f;
  for (int i = 0; i < Hn; ++i) m = fmaxf(m, fabsf(w[i]));
  sq[t] = fmaxf(m, 1e-30f) / 127.f;
}

// Whh -> i8 A-frags. WF8[dir][w][frag=kt*8+m][lane] (uint4 = 16 x i8).
// m: g=m>>1, j=m&1; row = (g*16+2w+j)*16 + (lane&15); k = kt*64 + (lane>>4)*16 + 0..15.
__global__ void k_prep_whh8(const float* __restrict__ whhF, const float* __restrict__ whhB,
                            const float* __restrict__ sq, uint4* __restrict__ WF8) {
  int t = blockIdx.x * blockDim.x + threadIdx.x;   // 0 .. 32767
  if (t >= 2 * 8 * 32 * 64) return;
  int lane = t & 63;
  int frag = (t >> 6) & 31;
  int w    = (t >> 11) & 7;
  int dir  = (t >> 14) & 1;
  int m  = frag & 7, kt = frag >> 3;
  int g = m >> 1, j = m & 1;
  int row = (g * 16 + 2 * w + j) * 16 + (lane & 15);
  int kb  = kt * 64 + (lane >> 4) * 16;
  const float* whh = dir ? whhB : whhF;
  const float* src = whh + (size_t)row * Hn + kb;
  float inv = 1.f / sq[dir * 1024 + row];          // = 127/rowmax
  uint pk[4];
#pragma unroll
  for (int q = 0; q < 4; ++q) {
    uint v = 0;
#pragma unroll
    for (int b = 0; b < 4; ++b) {
      float f = src[q * 4 + b] * inv;
      int iq = (int)rintf(fminf(fmaxf(f, -127.f), 127.f));
      v |= ((uint)(unsigned char)(signed char)iq) << (8 * b);
    }
    pk[q] = v;
  }
  WF8[t] = (uint4){pk[0], pk[1], pk[2], pk[3]};
}

__global__ void k_bad(float* __restrict__ out, int n) {
  int i = blockIdx.x * blockDim.x + threadIdx.x;
  if (i < n) out[i] = 54321.f;
}

// ---------------- phase 1: fp16 MFMA GEMM (unchanged) ----------------

__device__ __forceinline__ void gload_lds16(const void* g, void* l) {
  __builtin_amdgcn_global_load_lds((const __attribute__((address_space(1))) void*)g,
                                   (__attribute__((address_space(3))) void*)l, 16, 0, 0);
}

__global__ __launch_bounds__(256) void k_gemm(const ushort* __restrict__ A,
                                              const ushort* __restrict__ W,
                                              const float* __restrict__ biasc,
                                              ushort* __restrict__ xp) {
  __shared__ __align__(16) ushort As[128 * 32];
  __shared__ __align__(16) ushort Bs[128 * 32];
  const int bid = blockIdx.x;
  const int m0 = (bid >> 4) * 128;
  const int n0 = (bid & 15) * 128;
  const int tid = threadIdx.x;
  const int wid = tid >> 6, lane = tid & 63;
  const int wr = wid >> 1, wcq = wid & 1;
  const int l16 = lane & 15, lq = lane >> 4;

  f32x4 acc[4][4] = {};

  for (int kt = 0; kt < KT; kt += 32) {
    __syncthreads();
#pragma unroll
    for (int i = 0; i < 2; ++i) {
      int ch = wid * 2 + i;
      int p = ch * 64 + lane;
      int r = p >> 2, gp = p & 3;
      int gs = gp ^ ((r >> 1) & 3);
      gload_lds16(A + (size_t)(m0 + r) * KT + kt + gs * 8, (char*)As + ch * 1024);
      gload_lds16(W + (size_t)(n0 + r) * KT + kt + gs * 8, (char*)Bs + ch * 1024);
    }
    __syncthreads();

    half8 af[4], bfr[4];
#pragma unroll
    for (int mfi = 0; mfi < 4; ++mfi) {
      int row = wr * 64 + mfi * 16 + l16;
      int g = lq ^ ((row >> 1) & 3);
      af[mfi] = *(const half8*)((const char*)As + row * 64 + g * 16);
    }
#pragma unroll
    for (int nf = 0; nf < 4; ++nf) {
      int row = wcq * 64 + nf * 16 + l16;
      int g = lq ^ ((row >> 1) & 3);
      bfr[nf] = *(const half8*)((const char*)Bs + row * 64 + g * 16);
    }
#pragma unroll
    for (int mfi = 0; mfi < 4; ++mfi)
#pragma unroll
      for (int nf = 0; nf < 4; ++nf)
        acc[mfi][nf] = __builtin_amdgcn_mfma_f32_16x16x32_f16(af[mfi], bfr[nf], acc[mfi][nf], 0, 0, 0);
  }

#pragma unroll
  for (int nf = 0; nf < 4; ++nf) {
    int col = n0 + wcq * 64 + nf * 16 + l16;
    float bv = biasc[col];
#pragma unroll
    for (int mfi = 0; mfi < 4; ++mfi) {
      int rbase = m0 + wr * 64 + mfi * 16 + lq * 4;
#pragma unroll
      for (int i = 0; i < 4; ++i)
        xp[(size_t)(rbase + i) * NC + col] = f2h(acc[mfi][nf][i] + bv);
    }
  }
}

// ---------------- phase 2: zero-comm i8 MFMA recurrence, pipelined step ----------------
// bid: dir = &1, bl = >>1. Wave w owns outputs 32w..32w+31 (tiles g*16+2w+j).
// Per step: B-frag reads -> xp(t+1) prefetch -> j0 MFMAs -> j0 bounce -> j1 MFMAs
// -> j1 bounce -> gates (regs only) -> act (rcp) -> h write -> barrier.

__global__ __launch_bounds__(512, 2) void k_lstm(const uint4* __restrict__ WF8,
                                                 const float* __restrict__ sq,
                                                 const ushort* __restrict__ xp,
                                                 float* __restrict__ out,
                                                 int b_base) {
  const int dir = blockIdx.x & 1;
  const int bl  = blockIdx.x >> 1;
  const int tid = threadIdx.x;
  const int w    = tid >> 6;
  const int lane = tid & 63;
  const int lq   = lane >> 4;
  const int n    = lane & 31;          // this lane's output (2x redundant)

  __shared__ __align__(16) char hq[2][256];    // i8 h, parity double-buffered
  __shared__ __align__(16) int  gbuf[8][128];  // i32 gate bounce, per-wave

  // ---- persistent weights: all 32 i8 frags in registers ----
  const uint4* wfb = WF8 + (size_t)((dir * 8 + w) * 32) * 64 + lane;
  uint4 wA[32];
#pragma unroll
  for (int f = 0; f < 32; ++f) wA[f] = wfb[(size_t)f * 64];

  // per-output dequant scales (4 gate rows), includes the 1/127 h-scale
  float fdq[4];
#pragma unroll
  for (int g = 0; g < 4; ++g)
    fdq[g] = sq[dir * 1024 + g * 256 + 32 * w + n] * (1.f / 127.f);

  if (tid < 128) ((uint*)hq)[tid] = 0;         // h_{-1} = 0 (both buffers)
  float creg = 0.f;
  __syncthreads();

  const int dstep = dir ? -1 : 1;
  const int t0 = dir ? (Tn - 1) : 0;
  const ptrdiff_t xstr = (ptrdiff_t)dstep * NC;
  const ptrdiff_t ostr = (ptrdiff_t)dstep * 512;
  const ushort* px = xp + (size_t)(bl * Tn + t0) * NC + dir * 1024 + 32 * w + n;
  float* pout = out + (size_t)((b_base + bl) * Tn + t0) * 512 + dir * 256 + 32 * w + n;

  // preload xp for t=0 (fp32)
  float xc0 = h2f(px[0]), xc1 = h2f(px[256]), xc2 = h2f(px[512]), xc3 = h2f(px[768]);

  int cur = 0;
#pragma unroll 1
  for (int t = 0; t < Tn; ++t) {
    // B-frags: 16 i8 h-values per kt (uniform per lane-quad)
    uint4 bq[4];
#pragma unroll
    for (int kt = 0; kt < 4; ++kt)
      bq[kt] = *(const uint4*)(hq[cur] + kt * 64 + lq * 16);

    // prefetch xp for t+1 (consumed at NEXT step's tail: ~2 phases of cover)
    float xn0 = 0.f, xn1 = 0.f, xn2 = 0.f, xn3 = 0.f;
    if (t + 1 < Tn) {
      px += xstr;
      xn0 = h2f(px[0]); xn1 = h2f(px[256]); xn2 = h2f(px[512]); xn3 = h2f(px[768]);
    }

    i32x4 acc[8];
#pragma unroll
    for (int m = 0; m < 8; ++m) acc[m] = (i32x4){0, 0, 0, 0};

    // j=0 chains (m = 0,2,4,6)
#pragma unroll
    for (int kt = 0; kt < 4; ++kt)
#pragma unroll
      for (int m = 0; m < 8; m += 2)
        acc[m] = mfi8(wA[kt * 8 + m], bq[kt], acc[m]);
    // j0 bounce early: write hides under j1 MFMAs (slots g*32 + 0 + lq*4)
    if ((lane & 15) == 0) {
#pragma unroll
      for (int m = 0; m < 8; m += 2)
        *(i32x4*)&gbuf[w][(m >> 1) * 32 + lq * 4] = acc[m];
    }
    // j=1 chains (m = 1,3,5,7)
#pragma unroll
    for (int kt = 0; kt < 4; ++kt)
#pragma unroll
      for (int m = 1; m < 8; m += 2)
        acc[m] = mfi8(wA[kt * 8 + m], bq[kt], acc[m]);
    if ((lane & 15) == 0) {
#pragma unroll
      for (int m = 1; m < 8; m += 2)
        *(i32x4*)&gbuf[w][(m >> 1) * 32 + 16 + lq * 4] = acc[m];
    }

    // gates for output n (slot = g*32 + n); same-wave LDS dep (compiler lgkmcnt)
    float gi = (float)gbuf[w][0 * 32 + n] * fdq[0] + xc0;
    float gf = (float)gbuf[w][1 * 32 + n] * fdq[1] + xc1;
    float gg = (float)gbuf[w][2 * 32 + n] * fdq[2] + xc2;
    float go = (float)gbuf[w][3 * 32 + n] * fdq[3] + xc3;
    float iv = sigr_(gi), fv = sigr_(gf), gv = tanhr_(gg), ov = sigr_(go);
    creg = fv * creg + iv * gv;
    float h = ov * tanhr_(creg);
    if (lane < 32) {
      *pout = h;                                   // fp32 output (drains lazily)
      int q = (int)rintf(h * 127.f);               // |h|<1 -> q in [-127,127]
      hq[cur ^ 1][32 * w + n] = (char)q;           // i8 h for next step
    }
    pout += ostr;
    xc0 = xn0; xc1 = xn1; xc2 = xn2; xc3 = xn3;
    barrier_lgkm();                                // h_t visible to all waves
    cur ^= 1;
  }
}

// ---------------- host ----------------

extern "C" void kernel_launch(void* const* d_in, const int* in_sizes, int n_in,
                              void* d_out, int out_size, void* d_ws, size_t ws_size,
                              hipStream_t stream) {
  const float* x     = (const float*)d_in[0];
  const float* Wih_f = (const float*)d_in[1];
  const float* Whh_f = (const float*)d_in[2];
  const float* bih_f = (const float*)d_in[3];
  const float* bhh_f = (const float*)d_in[4];
  const float* Wih_b = (const float*)d_in[5];
  const float* Whh_b = (const float*)d_in[6];
  const float* bib_b = (const float*)d_in[7];
  const float* bhh_b = (const float*)d_in[8];
  float* out = (float*)d_out;

  const size_t szW16  = (size_t)NC * KT * 2;            // 2 MiB
  const size_t szBias = (size_t)NC * 4;
  const size_t szSq   = 2048 * 4;                       // 8 KiB row scales
  const size_t szWF8  = (size_t)2 * 8 * 32 * 64 * 16;   // 512 KiB i8 frag buffer

  int c = 0;
  size_t szA16 = 0, szXp = 0;
  for (int cc = 1; cc <= 16; cc *= 2) {
    size_t a = (size_t)(Bn / cc) * Tn * KT * 2;
    size_t p = (size_t)(Bn / cc) * Tn * NC * 2;
    if (szW16 + szBias + szSq + szWF8 + a + p <= ws_size) { c = cc; szA16 = a; szXp = p; break; }
  }
  if (c == 0) {
    k_bad<<<(out_size + 255) / 256, 256, 0, stream>>>(out, out_size);
    return;
  }

  char* ws = (char*)d_ws;
  ushort* W16   = (ushort*)ws;
  float*  biasc = (float*)(ws + szW16);
  float*  sq    = (float*)(ws + szW16 + szBias);
  uint4*  WF8   = (uint4*)(ws + szW16 + szBias + szSq);
  ushort* A16   = (ushort*)(ws + szW16 + szBias + szSq + szWF8);
  ushort* xp    = (ushort*)(ws + szW16 + szBias + szSq + szWF8 + szA16);

  {
    long n4 = (long)NC * (KT / 4);
    k_prep_w<<<(int)((n4 + 255) / 256), 256, 0, stream>>>(Wih_f, Wih_b, bih_f, bhh_f,
                                                          bib_b, bhh_b, W16, biasc);
  }
  k_scale<<<8, 256, 0, stream>>>(Whh_f, Whh_b, sq);
  k_prep_whh8<<<(2 * 8 * 32 * 64) / 256, 256, 0, stream>>>(Whh_f, Whh_b, sq, WF8);

  const int sizeB = Bn / c;
  for (int cb = 0; cb < c; ++cb) {
    const int b_base = cb * sizeB;
    {
      long nquad = (long)sizeB * Tn * KT / 4;
      k_prep_a<<<(int)((nquad + 255) / 256), 256, 0, stream>>>(
          x + (size_t)b_base * Tn * Dn, A16, nquad);
    }
    k_gemm<<<dim3(sizeB * 8 * 16), dim3(256), 0, stream>>>(A16, W16, biasc, xp);
    k_lstm<<<dim3(2 * sizeB), dim3(512), 0, stream>>>(WF8, sq, xp, out, b_base);
  }
}